// Round 8
// baseline (262.886 us; speedup 1.0000x reference)
//
#include <hip/hip_runtime.h>
#include <hip/hip_fp16.h>
#include <stdint.h>

#define O_FEAT 4096
#define I_FEAT 4096
#define M_DIM  2048
#define K_DIM  4096
#define BK 64

typedef __attribute__((ext_vector_type(8))) short short8;   // 8 x bf16 (4 VGPRs)
typedef __attribute__((ext_vector_type(2))) short short2v;  // 2 x bf16 (1 VGPR)
typedef __attribute__((ext_vector_type(4))) float floatx4;  // MFMA accumulator

#define AS1 __attribute__((address_space(1)))
#define AS3 __attribute__((address_space(3)))

__device__ __forceinline__ uint16_t f32_to_bf16(float f) {
    uint32_t u = __builtin_bit_cast(uint32_t, f);
    u = (u + 0x7FFFu + ((u >> 16) & 1u)) >> 16;   // round-to-nearest-even
    return (uint16_t)u;
}
__device__ __forceinline__ float bf16_to_f32(uint16_t h) {
    uint32_t u = ((uint32_t)h) << 16;
    return __builtin_bit_cast(float, u);
}

// async global->LDS, 16B per lane; LDS dest = wave-uniform base + lane*16
__device__ __forceinline__ void load_lds16(const uint16_t* gptr, uint16_t* ldsptr) {
    __builtin_amdgcn_global_load_lds((const AS1 uint32_t*)gptr,
                                     (AS3 uint32_t*)ldsptr, 16, 0, 0);
}

// ---------------------------------------------------------------------------
// Kernel 1 (fused): blocks [0,8192) dequant int4 -> bf16 W;
//                   blocks [8192,12288) convert x fp32 -> bf16 Xb.
// Probe-adaptive packed format (uint8 raw vs int32-widened).
// ---------------------------------------------------------------------------
__global__ __launch_bounds__(256) void prep_kernel(
        const void*  __restrict__ packed,
        const float* __restrict__ scales,
        const float* __restrict__ x,
        uint16_t*    __restrict__ W,
        uint16_t*    __restrict__ Xb) {
    if (blockIdx.x < 8192) {
        const int lane = threadIdx.x & 63;
        uint32_t probe = ((const uint32_t*)packed)[lane];
        const bool int32mode = (__ballot(probe >= 256u) == 0ull);

        int idx = blockIdx.x * 256 + threadIdx.x;       // 2,097,152 threads
        float s = scales[idx >> 9];                     // 512 byte-quads per row

        uint32_t bytes4;
        if (int32mode) {
            uint4 w = ((const uint4*)packed)[idx];      // 4 int32, each 0..255
            bytes4 = (w.x & 0xFFu) | ((w.y & 0xFFu) << 8) |
                     ((w.z & 0xFFu) << 16) | ((w.w & 0xFFu) << 24);
        } else {
            bytes4 = ((const uint32_t*)packed)[idx];
        }

        uint16_t o[8];
#pragma unroll
        for (int b = 0; b < 4; ++b) {
            int byte = (bytes4 >> (8 * b)) & 0xFF;
            o[2 * b]     = f32_to_bf16((float)((byte & 0xF) - 8) * s);  // low -> even
            o[2 * b + 1] = f32_to_bf16((float)((byte >> 4) - 8) * s);   // high -> odd
        }
        uint4 v;
        v.x = (uint32_t)o[0] | ((uint32_t)o[1] << 16);
        v.y = (uint32_t)o[2] | ((uint32_t)o[3] << 16);
        v.z = (uint32_t)o[4] | ((uint32_t)o[5] << 16);
        v.w = (uint32_t)o[6] | ((uint32_t)o[7] << 16);
        ((uint4*)W)[idx] = v;
    } else {
        int idx = (blockIdx.x - 8192) * 256 + threadIdx.x;   // 1,048,576 threads
        float4 v0 = ((const float4*)x)[2 * idx];
        float4 v1 = ((const float4*)x)[2 * idx + 1];
        uint4 o;
        o.x = (uint32_t)f32_to_bf16(v0.x) | ((uint32_t)f32_to_bf16(v0.y) << 16);
        o.y = (uint32_t)f32_to_bf16(v0.z) | ((uint32_t)f32_to_bf16(v0.w) << 16);
        o.z = (uint32_t)f32_to_bf16(v1.x) | ((uint32_t)f32_to_bf16(v1.y) << 16);
        o.w = (uint32_t)f32_to_bf16(v1.z) | ((uint32_t)f32_to_bf16(v1.w) << 16);
        ((uint4*)Xb)[idx] = o;
    }
}

// ---------------------------------------------------------------------------
// Kernel 2: scatter-add COO residual into bf16 W via packed-bf16 HW atomic
// (CAS fallback).  Probe-adaptive fp16/fp32 vals format.
// ---------------------------------------------------------------------------
__global__ __launch_bounds__(256) void scatter_kernel(
        const void* __restrict__ vals,
        const int*  __restrict__ rows,
        const int*  __restrict__ cols,
        const float* __restrict__ alpha,
        uint16_t*   __restrict__ W,
        int nnz) {
    const int lane = threadIdx.x & 63;
    float p = fabsf(((const float*)vals)[lane]);
    int cnt = __popcll(__ballot(p > 1e-4f && p < 1.0f));
    const bool f32mode = (cnt >= 32);

    int i = blockIdx.x * 256 + threadIdx.x;
    if (i >= nnz) return;
    float v = f32mode ? ((const float*)vals)[i]
                      : __half2float(((const __half*)vals)[i]);
    v *= alpha[0];
    int r = rows[i], c = cols[i];
    size_t elem = (size_t)r * I_FEAT + c;

#if __has_builtin(__builtin_amdgcn_global_atomic_fadd_v2bf16)
    const bool hi = (elem & 1);
    short b = (short)f32_to_bf16(v);
    short2v val;
    val[0] = hi ? (short)0 : b;
    val[1] = hi ? b : (short)0;
    __builtin_amdgcn_global_atomic_fadd_v2bf16(
        (AS1 short2v*)(W + (elem & ~(size_t)1)), val);
#else
    uint32_t* word = (uint32_t*)W + (elem >> 1);
    bool hi = (c & 1);
    uint32_t old = *word, assumed;
    do {
        assumed = old;
        uint16_t cur = hi ? (uint16_t)(assumed >> 16) : (uint16_t)(assumed & 0xFFFF);
        uint16_t nw  = f32_to_bf16(bf16_to_f32(cur) + v);
        uint32_t neww = hi ? ((assumed & 0x0000FFFFu) | ((uint32_t)nw << 16))
                           : ((assumed & 0xFFFF0000u) | (uint32_t)nw);
        old = atomicCAS(word, assumed, neww);
    } while (old != assumed);
#endif
}

// ---------------------------------------------------------------------------
// Kernel 3: C[M,N] = A[M,K] * B[N,K]^T  (bf16 in, fp32 out).
// R8: 128x128 tile, BK=64, DOUBLE-BUFFERED LDS + single barrier per iter.
// Prefetch for tile k+1 is issued right after the barrier and drained only at
// the NEXT barrier -> global latency overlaps one full compute phase
// (32 MFMA/wave).  LDS layout keeps R5's proven [128][32] slab pattern
// (2 slabs per BK=64 stage), staged via async global_load_lds width=16.
// ---------------------------------------------------------------------------
__global__ __launch_bounds__(256, 2) void gemm_bt_kernel(
        const uint16_t* __restrict__ A,   // [2048][4096] bf16
        const uint16_t* __restrict__ B,   // [4096][4096] bf16 (row-major [N][K])
        float* __restrict__ C) {          // [2048][4096] fp32
    __shared__ uint16_t As[2][2][128 * 32];   // [buf][slab] 32 KB
    __shared__ uint16_t Bs[2][2][128 * 32];   // [buf][slab] 32 KB

    const int tid  = threadIdx.x;
    const int wave = tid >> 6;
    const int lane = tid & 63;
    const int wm = wave >> 1, wn = wave & 1;           // 2x2 wave grid
    const int bm0 = blockIdx.y * 128;
    const int bn0 = blockIdx.x * 128;

    // staging (per slab, R5 pattern): chunk = 16 rows x 32 elems = 1 wave-load
    const int lrow = lane >> 2;          // 0..15
    const int lcol = (lane & 3) * 8;     // elem seg within 32-wide slab

    floatx4 acc[4][4];
#pragma unroll
    for (int i = 0; i < 4; ++i)
#pragma unroll
        for (int j = 0; j < 4; ++j) acc[i][j] = {0.f, 0.f, 0.f, 0.f};

    const int fr = lane & 15;            // fragment row within 16
    const int ko = (lane >> 4) * 8;      // fragment k offset within slab

    // prologue: prefetch k0 = 0 into buffer 0
#pragma unroll
    for (int s = 0; s < 2; ++s)
#pragma unroll
        for (int j = 0; j < 2; ++j) {
            const int chunk = wave * 2 + j;              // 0..7
            const int row = chunk * 16 + lrow;
            load_lds16(A + (size_t)(bm0 + row) * K_DIM + s * 32 + lcol,
                       &As[0][s][chunk * 512]);
            load_lds16(B + (size_t)(bn0 + row) * K_DIM + s * 32 + lcol,
                       &Bs[0][s][chunk * 512]);
        }

    for (int ki = 0; ki < K_DIM / BK; ++ki) {
        const int p = ki & 1;
        // drains own-wave vmcnt (prefetch of buf[p] issued last iter) then
        // barriers: buf[p] ready for all; buf[p^1] safe to overwrite.
        __syncthreads();

        // prefetch next stage into buf[p^1] (drained at NEXT barrier)
        const int kn = (ki + 1) * BK;
        if (kn < K_DIM) {
#pragma unroll
            for (int s = 0; s < 2; ++s)
#pragma unroll
                for (int j = 0; j < 2; ++j) {
                    const int chunk = wave * 2 + j;
                    const int row = chunk * 16 + lrow;
                    load_lds16(A + (size_t)(bm0 + row) * K_DIM + kn + s * 32 + lcol,
                               &As[p ^ 1][s][chunk * 512]);
                    load_lds16(B + (size_t)(bn0 + row) * K_DIM + kn + s * 32 + lcol,
                               &Bs[p ^ 1][s][chunk * 512]);
                }
        }

        // compute on buf[p]: 2 slabs x 16 MFMA
#pragma unroll
        for (int s = 0; s < 2; ++s) {
            short8 af[4], bf[4];
#pragma unroll
            for (int i = 0; i < 4; ++i) {
                af[i] = *(const short8*)&As[p][s][(wm * 64 + i * 16 + fr) * 32 + ko];
                bf[i] = *(const short8*)&Bs[p][s][(wn * 64 + i * 16 + fr) * 32 + ko];
            }
#pragma unroll
            for (int i = 0; i < 4; ++i)
#pragma unroll
                for (int j = 0; j < 4; ++j)
                    acc[i][j] = __builtin_amdgcn_mfma_f32_16x16x32_bf16(
                        af[i], bf[j], acc[i][j], 0, 0, 0);
        }
    }

    // epilogue: C/D layout col=lane&15, row=(lane>>4)*4+reg   [m89/m91]
    const int cn = lane & 15;
    const int rb = (lane >> 4) * 4;
#pragma unroll
    for (int i = 0; i < 4; ++i)
#pragma unroll
        for (int j = 0; j < 4; ++j)
#pragma unroll
            for (int r = 0; r < 4; ++r) {
                const int row = bm0 + wm * 64 + i * 16 + rb + r;
                const int col = bn0 + wn * 64 + j * 16 + cn;
                C[(size_t)row * O_FEAT + col] = acc[i][j][r];
            }
}

// ---------------------------------------------------------------------------
extern "C" void kernel_launch(void* const* d_in, const int* in_sizes, int n_in,
                              void* d_out, int out_size, void* d_ws, size_t ws_size,
                              hipStream_t stream) {
    const float* x      = (const float*)d_in[0];
    const void*  packed = d_in[1];
    const float* scales = (const float*)d_in[2];
    const void*  vals   = d_in[3];
    const int*   rows   = (const int*)d_in[4];
    const int*   cols   = (const int*)d_in[5];
    const float* alpha  = (const float*)d_in[6];
    float*       out    = (float*)d_out;
    const int nnz = in_sizes[3];

    uint16_t* W  = (uint16_t*)d_ws;                                        // 32 MB
    uint16_t* Xb = (uint16_t*)((char*)d_ws + (size_t)O_FEAT * I_FEAT * 2); // 16 MB

    // 1) fused dequant (blocks 0..8191) + x conversion (blocks 8192..12287)
    prep_kernel<<<12288, 256, 0, stream>>>(packed, scales, x, W, Xb);
    // 2) scatter sparse residual into W (packed bf16 hardware atomics)
    scatter_kernel<<<(nnz + 255) / 256, 256, 0, stream>>>(vals, rows, cols, alpha, W, nnz);
    // 3) GEMM: out = Xb (2048x4096) * W^T (4096x4096), 128x128 tiles, dbuf
    gemm_bt_kernel<<<dim3(O_FEAT / 128, M_DIM / 128), 256, 0, stream>>>(Xb, W, out);
}

// Round 9
// 245.926 us; speedup vs baseline: 1.0690x; 1.0690x over previous
//
#include <hip/hip_runtime.h>
#include <hip/hip_fp16.h>
#include <stdint.h>

#define O_FEAT 4096
#define I_FEAT 4096
#define M_DIM  2048
#define K_DIM  4096

typedef __attribute__((ext_vector_type(8))) short short8;   // 8 x bf16 (4 VGPRs)
typedef __attribute__((ext_vector_type(2))) short short2v;  // 2 x bf16 (1 VGPR)
typedef __attribute__((ext_vector_type(4))) float floatx4;  // MFMA accumulator

#define AS1 __attribute__((address_space(1)))
#define AS3 __attribute__((address_space(3)))

__device__ __forceinline__ uint16_t f32_to_bf16(float f) {
    uint32_t u = __builtin_bit_cast(uint32_t, f);
    u = (u + 0x7FFFu + ((u >> 16) & 1u)) >> 16;   // round-to-nearest-even
    return (uint16_t)u;
}
__device__ __forceinline__ float bf16_to_f32(uint16_t h) {
    uint32_t u = ((uint32_t)h) << 16;
    return __builtin_bit_cast(float, u);
}

// async global->LDS, 16B per lane; LDS dest = wave-uniform base + lane*16
__device__ __forceinline__ void load_lds16(const uint16_t* gptr, uint16_t* ldsptr) {
    __builtin_amdgcn_global_load_lds((const AS1 uint32_t*)gptr,
                                     (AS3 uint32_t*)ldsptr, 16, 0, 0);
}

// ---------------------------------------------------------------------------
// Kernel 1: dequant int4 -> bf16 W.  Probe-adaptive input format (uint8 raw
// vs int32-widened) — wave-uniform, deterministic, graph-safe.
// ---------------------------------------------------------------------------
__global__ __launch_bounds__(256) void dequant_kernel(
        const void*  __restrict__ packed,
        const float* __restrict__ scales,
        uint16_t*    __restrict__ W) {
    const int lane = threadIdx.x & 63;
    uint32_t probe = ((const uint32_t*)packed)[lane];
    const bool int32mode = (__ballot(probe >= 256u) == 0ull);

    int idx = blockIdx.x * 256 + threadIdx.x;       // 2,097,152 threads
    float s = scales[idx >> 9];                     // 512 byte-quads per row

    uint32_t bytes4;
    if (int32mode) {
        uint4 w = ((const uint4*)packed)[idx];      // 4 int32, each 0..255
        bytes4 = (w.x & 0xFFu) | ((w.y & 0xFFu) << 8) |
                 ((w.z & 0xFFu) << 16) | ((w.w & 0xFFu) << 24);
    } else {
        bytes4 = ((const uint32_t*)packed)[idx];
    }

    uint16_t o[8];
#pragma unroll
    for (int b = 0; b < 4; ++b) {
        int byte = (bytes4 >> (8 * b)) & 0xFF;
        o[2 * b]     = f32_to_bf16((float)((byte & 0xF) - 8) * s);  // low -> even
        o[2 * b + 1] = f32_to_bf16((float)((byte >> 4) - 8) * s);   // high -> odd
    }
    uint4 v;
    v.x = (uint32_t)o[0] | ((uint32_t)o[1] << 16);
    v.y = (uint32_t)o[2] | ((uint32_t)o[3] << 16);
    v.z = (uint32_t)o[4] | ((uint32_t)o[5] << 16);
    v.w = (uint32_t)o[6] | ((uint32_t)o[7] << 16);
    ((uint4*)W)[idx] = v;
}

// ---------------------------------------------------------------------------
// Kernel 2 (fused): blocks [0,3328) scatter-add COO residual into W via
// packed-bf16 HW atomic (CAS fallback); blocks [3328,7424) convert x fp32 ->
// bf16 Xb.  The atomic-latency-bound scatter overlaps the BW-bound
// conversion within one dispatch.  Probe-adaptive fp16/fp32 vals format.
// ---------------------------------------------------------------------------
#define SCATTER_BLOCKS 3328   // ceil(838860/256) = 3277, rounded up; guard below
__global__ __launch_bounds__(256) void scatter_xconv_kernel(
        const void*  __restrict__ vals,
        const int*   __restrict__ rows,
        const int*   __restrict__ cols,
        const float* __restrict__ alpha,
        const float* __restrict__ x,
        uint16_t*    __restrict__ W,
        uint16_t*    __restrict__ Xb,
        int nnz) {
    if (blockIdx.x < SCATTER_BLOCKS) {
        const int lane = threadIdx.x & 63;
        float p = fabsf(((const float*)vals)[lane]);
        int cnt = __popcll(__ballot(p > 1e-4f && p < 1.0f));
        const bool f32mode = (cnt >= 32);

        int i = blockIdx.x * 256 + threadIdx.x;
        if (i >= nnz) return;
        float v = f32mode ? ((const float*)vals)[i]
                          : __half2float(((const __half*)vals)[i]);
        v *= alpha[0];
        int r = rows[i], c = cols[i];
        size_t elem = (size_t)r * I_FEAT + c;

#if __has_builtin(__builtin_amdgcn_global_atomic_fadd_v2bf16)
        const bool hi = (elem & 1);
        short b = (short)f32_to_bf16(v);
        short2v val;
        val[0] = hi ? (short)0 : b;
        val[1] = hi ? b : (short)0;
        __builtin_amdgcn_global_atomic_fadd_v2bf16(
            (AS1 short2v*)(W + (elem & ~(size_t)1)), val);
#else
        uint32_t* word = (uint32_t*)W + (elem >> 1);
        bool hi = (c & 1);
        uint32_t old = *word, assumed;
        do {
            assumed = old;
            uint16_t cur = hi ? (uint16_t)(assumed >> 16) : (uint16_t)(assumed & 0xFFFF);
            uint16_t nw  = f32_to_bf16(bf16_to_f32(cur) + v);
            uint32_t neww = hi ? ((assumed & 0x0000FFFFu) | ((uint32_t)nw << 16))
                               : ((assumed & 0xFFFF0000u) | (uint32_t)nw);
            old = atomicCAS(word, assumed, neww);
        } while (old != assumed);
#endif
    } else {
        // ---- xconv: one thread per 8 floats, 4096 blocks ----
        int idx = (blockIdx.x - SCATTER_BLOCKS) * 256 + threadIdx.x;  // 1,048,576
        float4 v0 = ((const float4*)x)[2 * idx];
        float4 v1 = ((const float4*)x)[2 * idx + 1];
        uint4 o;
        o.x = (uint32_t)f32_to_bf16(v0.x) | ((uint32_t)f32_to_bf16(v0.y) << 16);
        o.y = (uint32_t)f32_to_bf16(v0.z) | ((uint32_t)f32_to_bf16(v0.w) << 16);
        o.z = (uint32_t)f32_to_bf16(v1.x) | ((uint32_t)f32_to_bf16(v1.y) << 16);
        o.w = (uint32_t)f32_to_bf16(v1.z) | ((uint32_t)f32_to_bf16(v1.w) << 16);
        ((uint4*)Xb)[idx] = o;
    }
}

// ---------------------------------------------------------------------------
// Kernel 3: C[M,N] = A[M,K] * B[N,K]^T  (bf16 in, fp32 out).
// R5-EXACT structure (best of 5 variants tried: 94 µs / ~731 TF): 128x128
// tile, BK=32, 2x2 waves, 16x16x32 MFMA, async global_load_lds width=16,
// 2-barrier K-loop.  R4 (reg prefetch), R7 (64x128, 4 blk/CU), R8 (LDS dbuf
// single-barrier) all regressed — this is the m97-structure plateau.
// ---------------------------------------------------------------------------
__global__ __launch_bounds__(256, 2) void gemm_bt_kernel(
        const uint16_t* __restrict__ A,   // [2048][4096] bf16
        const uint16_t* __restrict__ B,   // [4096][4096] bf16 (row-major [N][K])
        float* __restrict__ C) {          // [2048][4096] fp32
    __shared__ uint16_t As[128 * 32];
    __shared__ uint16_t Bs[128 * 32];

    const int tid  = threadIdx.x;
    const int wave = tid >> 6;
    const int lane = tid & 63;
    const int wm = wave >> 1, wn = wave & 1;           // 2x2 wave grid
    const int bm0 = blockIdx.y * 128;
    const int bn0 = blockIdx.x * 128;

    const int lrow = lane >> 2;          // 0..15
    const int lcol = (lane & 3) * 8;     // elem offset within 32-wide K slab

    floatx4 acc[4][4];
#pragma unroll
    for (int i = 0; i < 4; ++i)
#pragma unroll
        for (int j = 0; j < 4; ++j) acc[i][j] = {0.f, 0.f, 0.f, 0.f};

    const int fr = lane & 15;            // fragment row within 16
    const int ko = (lane >> 4) * 8;      // fragment k offset

    for (int k0 = 0; k0 < K_DIM; k0 += 32) {
        __syncthreads();                 // prior LDS reads done before overwrite
#pragma unroll
        for (int j = 0; j < 2; ++j) {
            const int chunk = wave * 2 + j;          // 0..7 (16 rows each)
            const int row = chunk * 16 + lrow;
            load_lds16(A + (size_t)(bm0 + row) * K_DIM + k0 + lcol,
                       &As[chunk * 512]);
            load_lds16(B + (size_t)(bn0 + row) * K_DIM + k0 + lcol,
                       &Bs[chunk * 512]);
        }
        __syncthreads();                 // drains vmcnt for global_load_lds

        short8 af[4], bf[4];
#pragma unroll
        for (int i = 0; i < 4; ++i) {
            af[i] = *(const short8*)&As[(wm * 64 + i * 16 + fr) * 32 + ko];
            bf[i] = *(const short8*)&Bs[(wn * 64 + i * 16 + fr) * 32 + ko];
        }
#pragma unroll
        for (int i = 0; i < 4; ++i)
#pragma unroll
            for (int j = 0; j < 4; ++j)
                acc[i][j] = __builtin_amdgcn_mfma_f32_16x16x32_bf16(
                    af[i], bf[j], acc[i][j], 0, 0, 0);
    }

    // epilogue: C/D layout col=lane&15, row=(lane>>4)*4+reg   [m89/m91]
    const int cn = lane & 15;
    const int rb = (lane >> 4) * 4;
#pragma unroll
    for (int i = 0; i < 4; ++i)
#pragma unroll
        for (int j = 0; j < 4; ++j)
#pragma unroll
            for (int r = 0; r < 4; ++r) {
                const int row = bm0 + wm * 64 + i * 16 + rb + r;
                const int col = bn0 + wn * 64 + j * 16 + cn;
                C[(size_t)row * O_FEAT + col] = acc[i][j][r];
            }
}

// ---------------------------------------------------------------------------
extern "C" void kernel_launch(void* const* d_in, const int* in_sizes, int n_in,
                              void* d_out, int out_size, void* d_ws, size_t ws_size,
                              hipStream_t stream) {
    const float* x      = (const float*)d_in[0];
    const void*  packed = d_in[1];
    const float* scales = (const float*)d_in[2];
    const void*  vals   = d_in[3];
    const int*   rows   = (const int*)d_in[4];
    const int*   cols   = (const int*)d_in[5];
    const float* alpha  = (const float*)d_in[6];
    float*       out    = (float*)d_out;
    const int nnz = in_sizes[3];

    uint16_t* W  = (uint16_t*)d_ws;                                        // 32 MB
    uint16_t* Xb = (uint16_t*)((char*)d_ws + (size_t)O_FEAT * I_FEAT * 2); // 16 MB

    // 1) dequant int4 -> bf16 W
    dequant_kernel<<<8192, 256, 0, stream>>>(packed, scales, W);
    // 2) fused: scatter residual into W (blocks < 3328) + x -> bf16 (rest)
    scatter_xconv_kernel<<<SCATTER_BLOCKS + 4096, 256, 0, stream>>>(
        vals, rows, cols, alpha, x, W, Xb, nnz);
    // 3) GEMM: out = Xb (2048x4096) * W^T (4096x4096)
    gemm_bt_kernel<<<dim3(O_FEAT / 128, M_DIM / 128), 256, 0, stream>>>(Xb, W, out);
}